// Round 1
// baseline (225.005 us; speedup 1.0000x reference)
//
#include <hip/hip_runtime.h>
#include <math.h>

namespace {
constexpr int cB = 8, cS = 16, cP = 32, cN = 2048, cV = 2562;
constexpr int cK = 500;              // K_SAMPLE
constexpr int cJ = cS * cK;          // 8000 pred points per batch
constexpr int cJC = 4;               // j-chunks for global-loss kernel
constexpr int cJCH = cJ / cJC;       // 2000
constexpr float FINF = 3.402823466e+38f;

// workspace layout (float offsets)
constexpr int OFF_PRED = 0;                           // cB*cS*cK*3 = 192000
constexpr int OFF_CENT = OFF_PRED + cB * cS * cK * 3; // 192000 (len 384)
constexpr int OFF_VBAR = OFF_CENT + cB * cS * 3;      // 192384 (len 4)
constexpr int OFF_OBAR = OFF_VBAR + 4;                // 192388 (len 96)
constexpr int OFF_TOP3 = 192512;                      // len cB*cN*cJC*3 = 196608
constexpr int OFF_GM   = OFF_TOP3 + cB * cN * cJC * 3;// 389120 (len 64)
constexpr int OFF_PS   = OFF_GM + 64;                 // 389184 (len 256)
constexpr int OFF_REP  = OFF_PS + 256;                // 389440 (len 1)
} // namespace

// ---------- kernel 0: mean vertex + per-prototype mean offset ----------
__global__ void k_means(const float* __restrict__ verts,
                        const float* __restrict__ offs,
                        float* __restrict__ ws) {
  __shared__ float red[256];
  const int blk = blockIdx.x;  // 0..cP-1 -> obar[p], cP -> vbar
  const int tid = threadIdx.x;
  const float* src = (blk < cP) ? (offs + blk * cV * 3) : verts;
  float acc0 = 0.f, acc1 = 0.f, acc2 = 0.f;
  for (int v = tid; v < cV; v += 256) {
    acc0 += src[v * 3 + 0];
    acc1 += src[v * 3 + 1];
    acc2 += src[v * 3 + 2];
  }
  float* dst = (blk < cP) ? (ws + OFF_OBAR + blk * 3) : (ws + OFF_VBAR);
  float a[3] = {acc0, acc1, acc2};
  for (int c = 0; c < 3; ++c) {
    red[tid] = a[c];
    __syncthreads();
    for (int s = 128; s > 0; s >>= 1) {
      if (tid < s) red[tid] += red[tid + s];
      __syncthreads();
    }
    if (tid == 0) dst[c] = red[0] / (float)cV;
    __syncthreads();
  }
}

// ---------- kernel A: pred points (first 500 verts) + centroids ----------
__global__ void k_pred(const float* __restrict__ scales,
                       const float* __restrict__ transforms,
                       const float* __restrict__ pw,
                       const float* __restrict__ offs,
                       const float* __restrict__ verts,
                       float* __restrict__ ws) {
  const int bs = blockIdx.x;  // b*cS+s
  const int tid = threadIdx.x;
  __shared__ float sM[cP][9];
  __shared__ float sWT[cP][3];
  __shared__ float sC[3];
  if (tid < cP) {
    const int p = tid;
    const float* t = transforms + (bs * cP + p) * 6;
    const float w = pw[bs * cP + p];
    const float sc = scales[bs];
    const float a = t[3], b = t[4], c = t[5];
    const float ca = cosf(a), sa = sinf(a);
    const float cb = cosf(b), sb = sinf(b);
    const float cg = cosf(c), sg = sinf(c);
    const float f = w * sc;
    // R = Rx(a) @ Ry(b) @ Rz(c)
    sM[p][0] = f * (cb * cg);
    sM[p][1] = f * (-cb * sg);
    sM[p][2] = f * (sb);
    sM[p][3] = f * (ca * sg + sa * sb * cg);
    sM[p][4] = f * (ca * cg - sa * sb * sg);
    sM[p][5] = f * (-sa * cb);
    sM[p][6] = f * (sa * sg - ca * sb * cg);
    sM[p][7] = f * (sa * cg + ca * sb * sg);
    sM[p][8] = f * (ca * cb);
    sWT[p][0] = w * t[0];
    sWT[p][1] = w * t[1];
    sWT[p][2] = w * t[2];
  }
  __syncthreads();
  if (tid < 3) {
    float s = 0.f;
    for (int p = 0; p < cP; ++p) s += sWT[p][tid];
    sC[tid] = s;
  }
  __syncthreads();
  for (int k = tid; k < cK; k += blockDim.x) {
    const float x0 = verts[k * 3 + 0], x1 = verts[k * 3 + 1], x2 = verts[k * 3 + 2];
    float a0 = sC[0], a1 = sC[1], a2 = sC[2];
#pragma unroll 8
    for (int p = 0; p < cP; ++p) {
      const float* o = offs + (p * cV + k) * 3;
      const float d0 = x0 + o[0], d1 = x1 + o[1], d2 = x2 + o[2];
      a0 = fmaf(sM[p][0], d0, fmaf(sM[p][1], d1, fmaf(sM[p][2], d2, a0)));
      a1 = fmaf(sM[p][3], d0, fmaf(sM[p][4], d1, fmaf(sM[p][5], d2, a1)));
      a2 = fmaf(sM[p][6], d0, fmaf(sM[p][7], d1, fmaf(sM[p][8], d2, a2)));
    }
    float* pr = ws + OFF_PRED + (bs * cK + k) * 3;
    pr[0] = a0; pr[1] = a1; pr[2] = a2;
  }
  if (tid == 0) {
    const float* vb = ws + OFF_VBAR;
    float c0 = sC[0], c1 = sC[1], c2 = sC[2];
    for (int p = 0; p < cP; ++p) {
      const float* ob = ws + OFF_OBAR + p * 3;
      const float d0 = vb[0] + ob[0], d1 = vb[1] + ob[1], d2 = vb[2] + ob[2];
      c0 += sM[p][0] * d0 + sM[p][1] * d1 + sM[p][2] * d2;
      c1 += sM[p][3] * d0 + sM[p][4] * d1 + sM[p][5] * d2;
      c2 += sM[p][6] * d0 + sM[p][7] * d1 + sM[p][8] * d2;
    }
    float* ct = ws + OFF_CENT + bs * 3;
    ct[0] = c0; ct[1] = c1; ct[2] = c2;
  }
}

// ---------- kernel G: per-target partial top-3 over a j-chunk ----------
__global__ void k_global(const float* __restrict__ target,
                         float* __restrict__ ws) {
  __shared__ float sP[cJCH * 3];  // 24 KB
  const int nb = blockIdx.x, jc = blockIdx.y, b = blockIdx.z;
  const int tid = threadIdx.x;
  const float* pr = ws + OFF_PRED + (b * cJ + jc * cJCH) * 3;
  for (int i = tid; i < cJCH * 3; i += 256) sP[i] = pr[i];
  __syncthreads();
  const int n = nb * 256 + tid;
  const float* tg = target + (b * cN + n) * 3;
  const float x = tg[0], y = tg[1], z = tg[2];
  float t0 = FINF, t1 = FINF, t2 = FINF;
  for (int j = 0; j < cJCH; ++j) {
    const float dx = x - sP[j * 3 + 0];
    const float dy = y - sP[j * 3 + 1];
    const float dz = z - sP[j * 3 + 2];
    const float d = fmaf(dx, dx, fmaf(dy, dy, dz * dz));
    // branchless sorted-insert into (t0 <= t1 <= t2)
    const float h0 = fmaxf(t0, d); t0 = fminf(t0, d);
    const float h1 = fmaxf(t1, h0); t1 = fminf(t1, h0);
    t2 = fminf(t2, h1);
  }
  float* o = ws + OFF_TOP3 + ((b * cN + n) * cJC + jc) * 3;
  o[0] = t0; o[1] = t1; o[2] = t2;
}

// ---------- kernel GM: merge partial top-3, block-sum ----------
__global__ void k_gmerge(float* __restrict__ ws) {
  __shared__ float red[256];
  const int tid = threadIdx.x;
  const int idx = blockIdx.x * 256 + tid;  // over cB*cN
  const float* tp = ws + OFF_TOP3 + idx * cJC * 3;
  float t0 = FINF, t1 = FINF, t2 = FINF;
#pragma unroll
  for (int q = 0; q < cJC * 3; ++q) {
    const float d = tp[q];
    const float h0 = fmaxf(t0, d); t0 = fminf(t0, d);
    const float h1 = fmaxf(t1, h0); t1 = fminf(t1, h0);
    t2 = fminf(t2, h1);
  }
  red[tid] = t0 + t1 + t2;
  __syncthreads();
  for (int s = 128; s > 0; s >>= 1) {
    if (tid < s) red[tid] += red[tid + s];
    __syncthreads();
  }
  if (tid == 0) ws[OFF_GM + blockIdx.x] = red[0];
}

// ---------- kernel P: per-pred min over all targets, block-sum ----------
__global__ void k_perslot(const float* __restrict__ target,
                          float* __restrict__ ws) {
  __shared__ float sT[cN * 3];  // 24 KB
  const int jb = blockIdx.x;    // 0..31 (250 j each)
  const int b = blockIdx.y;
  const int tid = threadIdx.x;
  const float* tg = target + b * cN * 3;
  for (int i = tid; i < cN * 3; i += 256) sT[i] = tg[i];
  __syncthreads();
  const int j = jb * 250 + tid;
  float m = FINF;
  if (tid < 250) {
    const float* pr = ws + OFF_PRED + (b * cJ + j) * 3;
    const float x = pr[0], y = pr[1], z = pr[2];
    for (int n = 0; n < cN; ++n) {
      const float dx = x - sT[n * 3 + 0];
      const float dy = y - sT[n * 3 + 1];
      const float dz = z - sT[n * 3 + 2];
      m = fminf(m, fmaf(dx, dx, fmaf(dy, dy, dz * dz)));
    }
  }
  __shared__ float red[256];
  red[tid] = (tid < 250) ? m : 0.f;
  __syncthreads();
  for (int s = 128; s > 0; s >>= 1) {
    if (tid < s) red[tid] += red[tid + s];
    __syncthreads();
  }
  if (tid == 0) ws[OFF_PS + b * 32 + jb] = red[0];
}

// ---------- kernel R: repulsion loss numerator ----------
__global__ void k_rep(float* __restrict__ ws) {
  __shared__ float red[256];
  const int tid = threadIdx.x;
  const float* cent = ws + OFF_CENT;
  float acc = 0.f;
  for (int idx = tid; idx < cB * cS * cS; idx += 256) {
    const int b = idx / (cS * cS);
    const int r = idx % (cS * cS);
    const int i = r / cS, jj = r % cS;
    if (i == jj) continue;
    const float* ci = cent + (b * cS + i) * 3;
    const float* cj = cent + (b * cS + jj) * 3;
    const float dx = ci[0] - cj[0], dy = ci[1] - cj[1], dz = ci[2] - cj[2];
    const float d = sqrtf(fmaf(dx, dx, fmaf(dy, dy, dz * dz)));
    acc += expf(5.0f * fmaxf(0.5f - d, 0.0f));
  }
  red[tid] = acc;
  __syncthreads();
  for (int s = 128; s > 0; s >>= 1) {
    if (tid < s) red[tid] += red[tid + s];
    __syncthreads();
  }
  if (tid == 0) ws[OFF_REP] = red[0];
}

// ---------- kernel F: combine ----------
__global__ void k_final(float* __restrict__ ws, float* __restrict__ out) {
  __shared__ float red[256];
  const int tid = threadIdx.x;
  red[tid] = (tid < 64) ? ws[OFF_GM + tid] : 0.f;
  __syncthreads();
  for (int s = 128; s > 0; s >>= 1) {
    if (tid < s) red[tid] += red[tid + s];
    __syncthreads();
  }
  float gsum = 0.f;
  if (tid == 0) gsum = red[0];
  __syncthreads();
  red[tid] = ws[OFF_PS + tid];
  __syncthreads();
  for (int s = 128; s > 0; s >>= 1) {
    if (tid < s) red[tid] += red[tid + s];
    __syncthreads();
  }
  if (tid == 0) {
    const float global_loss = gsum / (float)(cB * cN * 3);
    const float per_slot = red[0] / (float)(cB * cS * cK);
    const float rep = ws[OFF_REP] / (float)(cB * cS * (cS - 1));
    out[0] = 0.7f * global_loss + 0.3f * per_slot + 0.2f * rep;
  }
}

extern "C" void kernel_launch(void* const* d_in, const int* in_sizes, int n_in,
                              void* d_out, int out_size, void* d_ws, size_t ws_size,
                              hipStream_t stream) {
  const float* scales     = (const float*)d_in[0];  // (B,S,1)
  const float* transforms = (const float*)d_in[1];  // (B,S,P,6)
  const float* pw         = (const float*)d_in[2];  // (B,S,P)
  const float* offs       = (const float*)d_in[3];  // (P,V,3)
  const float* target     = (const float*)d_in[4];  // (B,N,3)
  const float* verts      = (const float*)d_in[5];  // (V,3)
  float* out = (float*)d_out;
  float* ws = (float*)d_ws;

  k_means<<<cP + 1, 256, 0, stream>>>(verts, offs, ws);
  k_pred<<<cB * cS, 256, 0, stream>>>(scales, transforms, pw, offs, verts, ws);
  k_global<<<dim3(cN / 256, cJC, cB), 256, 0, stream>>>(target, ws);
  k_perslot<<<dim3(32, cB), 256, 0, stream>>>(target, ws);
  k_rep<<<1, 256, 0, stream>>>(ws);
  k_gmerge<<<(cB * cN) / 256, 256, 0, stream>>>(ws);
  k_final<<<1, 256, 0, stream>>>(ws, out);
}

// Round 2
// 76.459 us; speedup vs baseline: 2.9428x; 2.9428x over previous
//
#include <hip/hip_runtime.h>
#include <math.h>

namespace {
constexpr int cB = 8, cS = 16, cP = 32, cN = 2048, cV = 2562;
constexpr int cK = 500;              // K_SAMPLE
constexpr int cJ = cS * cK;          // 8000 pred points per batch
constexpr int cJC = 16;              // j-chunks for global-loss kernel (500 each)
constexpr int cJCH = cJ / cJC;       // 500
constexpr int cNC = 8;               // target-chunks for perslot (256 each)
constexpr int cNCH = cN / cNC;       // 256
constexpr int cJPAD = 8192;          // padded j count for perslot partials
constexpr float FINF = 3.402823466e+38f;

// workspace layout (float offsets, all float4-aligned where needed)
constexpr int OFF_PRED4 = 0;                                // cB*cJ*4 = 256000
constexpr int OFF_TGT4  = OFF_PRED4 + cB * cJ * 4;          // 256000, len cB*cN*4 = 65536
constexpr int OFF_CENT  = OFF_TGT4 + cB * cN * 4;           // 321536, len 384
constexpr int OFF_VBAR  = OFF_CENT + cB * cS * 3;           // len 4
constexpr int OFF_OBAR  = OFF_VBAR + 4;                     // len 96
constexpr int OFF_T3    = 322048;                           // cB*cN*cJC*3 = 786432
constexpr int OFF_PSP   = OFF_T3 + cB * cN * cJC * 3;       // cB*cNC*cJPAD = 524288
constexpr int OFF_GM    = OFF_PSP + cB * cNC * cJPAD;       // 64
constexpr int OFF_PS    = OFF_GM + 64;                      // 256
} // namespace

__device__ __forceinline__ float block_sum(float v, float* red, int tid) {
  red[tid] = v;
  __syncthreads();
  for (int s = 128; s > 0; s >>= 1) {
    if (tid < s) red[tid] += red[tid + s];
    __syncthreads();
  }
  return red[0];
}

// ---------- kernel PREP: means (blocks 0..32) + target float4 (blocks 33..96) ----------
__global__ void k_prep(const float* __restrict__ verts,
                       const float* __restrict__ offs,
                       const float* __restrict__ target,
                       float* __restrict__ ws) {
  const int blk = blockIdx.x;
  const int tid = threadIdx.x;
  if (blk <= cP) {
    __shared__ float red[256];
    const float* src = (blk < cP) ? (offs + blk * cV * 3) : verts;
    float acc0 = 0.f, acc1 = 0.f, acc2 = 0.f;
    for (int v = tid; v < cV; v += 256) {
      acc0 += src[v * 3 + 0];
      acc1 += src[v * 3 + 1];
      acc2 += src[v * 3 + 2];
    }
    float* dst = (blk < cP) ? (ws + OFF_OBAR + blk * 3) : (ws + OFF_VBAR);
    float a[3] = {acc0, acc1, acc2};
    for (int c = 0; c < 3; ++c) {
      float s = block_sum(a[c], red, tid);
      if (tid == 0) dst[c] = s / (float)cV;
      __syncthreads();
    }
  } else {
    const int idx = (blk - (cP + 1)) * 256 + tid;  // over cB*cN = 16384
    const float x = target[idx * 3 + 0];
    const float y = target[idx * 3 + 1];
    const float z = target[idx * 3 + 2];
    float4* o = (float4*)(ws + OFF_TGT4);
    o[idx] = make_float4(x, y, z, 0.5f * fmaf(x, x, fmaf(y, y, z * z)));
  }
}

// ---------- kernel A: pred float4 (first 500 verts) + centroids ----------
__global__ void k_pred(const float* __restrict__ scales,
                       const float* __restrict__ transforms,
                       const float* __restrict__ pw,
                       const float* __restrict__ offs,
                       const float* __restrict__ verts,
                       float* __restrict__ ws) {
  const int bs = blockIdx.x;  // b*cS+s
  const int tid = threadIdx.x;
  __shared__ float sM[cP][9];
  __shared__ float sWT[cP][3];
  __shared__ float sC[3];
  if (tid < cP) {
    const int p = tid;
    const float* t = transforms + (bs * cP + p) * 6;
    const float w = pw[bs * cP + p];
    const float sc = scales[bs];
    const float a = t[3], b = t[4], c = t[5];
    const float ca = cosf(a), sa = sinf(a);
    const float cb = cosf(b), sb = sinf(b);
    const float cg = cosf(c), sg = sinf(c);
    const float f = w * sc;
    sM[p][0] = f * (cb * cg);
    sM[p][1] = f * (-cb * sg);
    sM[p][2] = f * (sb);
    sM[p][3] = f * (ca * sg + sa * sb * cg);
    sM[p][4] = f * (ca * cg - sa * sb * sg);
    sM[p][5] = f * (-sa * cb);
    sM[p][6] = f * (sa * sg - ca * sb * cg);
    sM[p][7] = f * (sa * cg + ca * sb * sg);
    sM[p][8] = f * (ca * cb);
    sWT[p][0] = w * t[0];
    sWT[p][1] = w * t[1];
    sWT[p][2] = w * t[2];
  }
  __syncthreads();
  if (tid < 3) {
    float s = 0.f;
    for (int p = 0; p < cP; ++p) s += sWT[p][tid];
    sC[tid] = s;
  }
  __syncthreads();
  for (int k = tid; k < cK; k += blockDim.x) {
    const float x0 = verts[k * 3 + 0], x1 = verts[k * 3 + 1], x2 = verts[k * 3 + 2];
    float a0 = sC[0], a1 = sC[1], a2 = sC[2];
#pragma unroll 8
    for (int p = 0; p < cP; ++p) {
      const float* o = offs + (p * cV + k) * 3;
      const float d0 = x0 + o[0], d1 = x1 + o[1], d2 = x2 + o[2];
      a0 = fmaf(sM[p][0], d0, fmaf(sM[p][1], d1, fmaf(sM[p][2], d2, a0)));
      a1 = fmaf(sM[p][3], d0, fmaf(sM[p][4], d1, fmaf(sM[p][5], d2, a1)));
      a2 = fmaf(sM[p][6], d0, fmaf(sM[p][7], d1, fmaf(sM[p][8], d2, a2)));
    }
    float4* pr = (float4*)(ws + OFF_PRED4);
    pr[bs * cK + k] =
        make_float4(a0, a1, a2, 0.5f * fmaf(a0, a0, fmaf(a1, a1, a2 * a2)));
  }
  if (tid == 0) {
    const float* vb = ws + OFF_VBAR;
    float c0 = sC[0], c1 = sC[1], c2 = sC[2];
    for (int p = 0; p < cP; ++p) {
      const float* ob = ws + OFF_OBAR + p * 3;
      const float d0 = vb[0] + ob[0], d1 = vb[1] + ob[1], d2 = vb[2] + ob[2];
      c0 += sM[p][0] * d0 + sM[p][1] * d1 + sM[p][2] * d2;
      c1 += sM[p][3] * d0 + sM[p][4] * d1 + sM[p][5] * d2;
      c2 += sM[p][6] * d0 + sM[p][7] * d1 + sM[p][8] * d2;
    }
    float* ct = ws + OFF_CENT + bs * 3;
    ct[0] = c0; ct[1] = c1; ct[2] = c2;
  }
}

// ---------- kernel G: per-target partial top-3 s-values over a 500-j chunk ----------
// s = hp - t.p ; d2 = 2*(s + ht)  (monotone in s)
__global__ void __launch_bounds__(256) k_global(float* __restrict__ ws) {
  __shared__ float4 sP[cJCH];  // 8 KB
  const int nb = blockIdx.x, jc = blockIdx.y, b = blockIdx.z;
  const int tid = threadIdx.x;
  const float4* pr = (const float4*)(ws + OFF_PRED4) + b * cJ + jc * cJCH;
  for (int i = tid; i < cJCH; i += 256) sP[i] = pr[i];
  __syncthreads();
  const int n = nb * 256 + tid;  // 0..1023, second target at n+1024
  const float4* tg = (const float4*)(ws + OFF_TGT4) + b * cN;
  const float4 tA = tg[n];
  const float4 tB = tg[n + 1024];
  float a0 = FINF, a1 = FINF, a2 = FINF;
  float b0 = FINF, b1 = FINF, b2 = FINF;
  for (int j = 0; j < cJCH; ++j) {
    const float4 p = sP[j];
    const float sA = fmaf(-tA.x, p.x, fmaf(-tA.y, p.y, fmaf(-tA.z, p.z, p.w)));
    const float sB = fmaf(-tB.x, p.x, fmaf(-tB.y, p.y, fmaf(-tB.z, p.z, p.w)));
    float h;
    h = fmaxf(a0, sA); a0 = fminf(a0, sA);
    { const float h1 = fmaxf(a1, h); a1 = fminf(a1, h); a2 = fminf(a2, h1); }
    h = fmaxf(b0, sB); b0 = fminf(b0, sB);
    { const float h1 = fmaxf(b1, h); b1 = fminf(b1, h); b2 = fminf(b2, h1); }
  }
  float* oA = ws + OFF_T3 + ((b * cN + n) * cJC + jc) * 3;
  oA[0] = a0; oA[1] = a1; oA[2] = a2;
  float* oB = ws + OFF_T3 + ((b * cN + n + 1024) * cJC + jc) * 3;
  oB[0] = b0; oB[1] = b1; oB[2] = b2;
}

// ---------- kernel GM: merge 16 partial top-3s per target, clamp, block-sum ----------
__global__ void k_gmerge(float* __restrict__ ws) {
  __shared__ float red[256];
  const int tid = threadIdx.x;
  const int idx = blockIdx.x * 256 + tid;  // over cB*cN
  const float* tp = ws + OFF_T3 + idx * cJC * 3;
  float t0 = FINF, t1 = FINF, t2 = FINF;
#pragma unroll
  for (int q = 0; q < cJC * 3; ++q) {
    const float d = tp[q];
    const float h0 = fmaxf(t0, d); t0 = fminf(t0, d);
    const float h1 = fmaxf(t1, h0); t1 = fminf(t1, h0);
    t2 = fminf(t2, h1);
  }
  const float ht = ws[OFF_TGT4 + idx * 4 + 3];
  const float d0 = fmaxf(2.f * (t0 + ht), 0.f);
  const float d1 = fmaxf(2.f * (t1 + ht), 0.f);
  const float d2 = fmaxf(2.f * (t2 + ht), 0.f);
  const float s = block_sum(d0 + d1 + d2, red, tid);
  if (tid == 0) ws[OFF_GM + blockIdx.x] = s;
}

// ---------- kernel P: per-pred partial min of s over a 256-target chunk ----------
// s = ht - p.t ; min d2 = 2*(min s + hp)
__global__ void __launch_bounds__(256) k_perslot(float* __restrict__ ws) {
  __shared__ float4 sT[cNCH];  // 4 KB
  const int jb = blockIdx.x;   // 8 j-blocks of 1024
  const int nc = blockIdx.y;   // 8 target chunks
  const int b = blockIdx.z;
  const int tid = threadIdx.x;
  const float4* tg = (const float4*)(ws + OFF_TGT4) + b * cN + nc * cNCH;
  sT[tid] = tg[tid];
  __syncthreads();
  const float4* pr = (const float4*)(ws + OFF_PRED4) + b * cJ;
  float px[4], py[4], pz[4];
  float m[4] = {FINF, FINF, FINF, FINF};
#pragma unroll
  for (int q = 0; q < 4; ++q) {
    int j = jb * 1024 + q * 256 + tid;
    j = (j < cJ) ? j : (cJ - 1);
    const float4 p = pr[j];
    px[q] = p.x; py[q] = p.y; pz[q] = p.z;
  }
  for (int n = 0; n < cNCH; ++n) {
    const float4 t = sT[n];
#pragma unroll
    for (int q = 0; q < 4; ++q) {
      const float s = fmaf(-px[q], t.x, fmaf(-py[q], t.y, fmaf(-pz[q], t.z, t.w)));
      m[q] = fminf(m[q], s);
    }
  }
  float* o = ws + OFF_PSP + (b * cNC + nc) * cJPAD + jb * 1024 + tid;
#pragma unroll
  for (int q = 0; q < 4; ++q) o[q * 256] = m[q];
}

// ---------- kernel PM: merge 8 chunk-mins per pred, add |p|^2, block-sum ----------
__global__ void k_psmerge(float* __restrict__ ws) {
  __shared__ float red[256];
  const int tid = threadIdx.x;
  const int b = blockIdx.y;
  const int j = blockIdx.x * 256 + tid;  // 0..8191
  float contrib = 0.f;
  if (j < cJ) {
    float m = FINF;
#pragma unroll
    for (int nc = 0; nc < cNC; ++nc)
      m = fminf(m, ws[OFF_PSP + (b * cNC + nc) * cJPAD + j]);
    const float hp = ws[OFF_PRED4 + (b * cJ + j) * 4 + 3];
    contrib = fmaxf(2.f * (m + hp), 0.f);
  }
  const float s = block_sum(contrib, red, tid);
  if (tid == 0) ws[OFF_PS + b * 32 + blockIdx.x] = s;
}

// ---------- kernel F: repulsion + combine ----------
__global__ void k_final(float* __restrict__ ws, float* __restrict__ out) {
  __shared__ float red[256];
  const int tid = threadIdx.x;
  // repulsion from centroids
  const float* cent = ws + OFF_CENT;
  float acc = 0.f;
  for (int idx = tid; idx < cB * cS * cS; idx += 256) {
    const int b = idx / (cS * cS);
    const int r = idx % (cS * cS);
    const int i = r / cS, jj = r % cS;
    if (i == jj) continue;
    const float* ci = cent + (b * cS + i) * 3;
    const float* cj = cent + (b * cS + jj) * 3;
    const float dx = ci[0] - cj[0], dy = ci[1] - cj[1], dz = ci[2] - cj[2];
    const float d = sqrtf(fmaf(dx, dx, fmaf(dy, dy, dz * dz)));
    acc += expf(5.0f * fmaxf(0.5f - d, 0.0f));
  }
  const float repsum = block_sum(acc, red, tid);
  __syncthreads();
  const float gsum = block_sum((tid < 64) ? ws[OFF_GM + tid] : 0.f, red, tid);
  __syncthreads();
  const float pssum = block_sum(ws[OFF_PS + tid], red, tid);
  if (tid == 0) {
    const float global_loss = gsum / (float)(cB * cN * 3);
    const float per_slot = pssum / (float)(cB * cS * cK);
    const float rep = repsum / (float)(cB * cS * (cS - 1));
    out[0] = 0.7f * global_loss + 0.3f * per_slot + 0.2f * rep;
  }
}

extern "C" void kernel_launch(void* const* d_in, const int* in_sizes, int n_in,
                              void* d_out, int out_size, void* d_ws, size_t ws_size,
                              hipStream_t stream) {
  const float* scales     = (const float*)d_in[0];
  const float* transforms = (const float*)d_in[1];
  const float* pw         = (const float*)d_in[2];
  const float* offs       = (const float*)d_in[3];
  const float* target     = (const float*)d_in[4];
  const float* verts      = (const float*)d_in[5];
  float* out = (float*)d_out;
  float* ws = (float*)d_ws;

  k_prep<<<cP + 1 + (cB * cN) / 256, 256, 0, stream>>>(verts, offs, target, ws);
  k_pred<<<cB * cS, 256, 0, stream>>>(scales, transforms, pw, offs, verts, ws);
  k_global<<<dim3(cN / 512, cJC, cB), 256, 0, stream>>>(ws);
  k_perslot<<<dim3(cJPAD / 1024, cNC, cB), 256, 0, stream>>>(ws);
  k_gmerge<<<(cB * cN) / 256, 256, 0, stream>>>(ws);
  k_psmerge<<<dim3(cJPAD / 256, cB), 256, 0, stream>>>(ws);
  k_final<<<1, 256, 0, stream>>>(ws, out);
}

// Round 3
// 68.303 us; speedup vs baseline: 3.2942x; 1.1194x over previous
//
#include <hip/hip_runtime.h>
#include <math.h>

namespace {
constexpr int cB = 8, cS = 16, cP = 32, cN = 2048, cV = 2562;
constexpr int cK = 500;              // K_SAMPLE
constexpr int cJ = cS * cK;          // 8000 pred points per batch
constexpr int cJC = 16;              // j-chunks for global-loss kernel (500 each)
constexpr int cJCH = cJ / cJC;       // 500
constexpr int cNC = 8;               // target-chunks for perslot (256 each)
constexpr int cNCH = cN / cNC;       // 256
constexpr int cJPAD = 8192;          // padded j count for perslot partials
constexpr int cBN = cB * cN;         // 16384
constexpr float FINF = 3.402823466e+38f;

// workspace layout (float offsets)
constexpr int OFF_PRED4 = 0;                         // cB*cJ*4 = 256000
constexpr int OFF_TGT4  = 256000;                    // cBN*4 = 65536
constexpr int OFF_VBAR  = 321536;                    // 4
constexpr int OFF_OBAR  = 321540;                    // 96
constexpr int OFF_SM    = 321664;                    // 128*288 = 36864
constexpr int OFF_SC    = 358528;                    // 384
constexpr int OFF_T3    = 358912;                    // 48*cBN = 786432 (plane-major)
constexpr int OFF_PSP   = 1145344;                   // cB*cNC*cJPAD = 524288
constexpr int OFF_GM    = 1669632;                   // 64
constexpr int OFF_PS    = 1669696;                   // 256
} // namespace

__device__ __forceinline__ float block_sum(float v, float* red, int tid) {
  red[tid] = v;
  __syncthreads();
  for (int s = 128; s > 0; s >>= 1) {
    if (tid < s) red[tid] += red[tid + s];
    __syncthreads();
  }
  return red[0];
}

// branchless sorted top-3 insert: (t0<=t1<=t2) <- d   [4 VALU ops]
__device__ __forceinline__ void top3_insert(float& t0, float& t1, float& t2, float d) {
  const float nt2 = fminf(t2, fmaxf(t1, d));
  const float nt1 = __builtin_amdgcn_fmed3f(t0, t1, d);
  t0 = fminf(t0, d);
  t1 = nt1;
  t2 = nt2;
}

// ---------- kernel FRONT: role-split ----------
// blk 0..32   : per-prototype mean offsets (+ mean vertex)
// blk 33..96  : target float4 (x,y,z, |t|^2/2)
// blk 97..224 : pred float4 for bs = blk-97, store sM / sC
__global__ void __launch_bounds__(256) k_front(const float* __restrict__ scales,
                                               const float* __restrict__ transforms,
                                               const float* __restrict__ pw,
                                               const float* __restrict__ offs,
                                               const float* __restrict__ verts,
                                               const float* __restrict__ target,
                                               float* __restrict__ ws) {
  const int blk = blockIdx.x;
  const int tid = threadIdx.x;
  if (blk <= cP) {
    __shared__ float red[256];
    const float* src = (blk < cP) ? (offs + blk * cV * 3) : verts;
    float acc0 = 0.f, acc1 = 0.f, acc2 = 0.f;
    for (int v = tid; v < cV; v += 256) {
      acc0 += src[v * 3 + 0];
      acc1 += src[v * 3 + 1];
      acc2 += src[v * 3 + 2];
    }
    float* dst = (blk < cP) ? (ws + OFF_OBAR + blk * 3) : (ws + OFF_VBAR);
    float a[3] = {acc0, acc1, acc2};
    for (int c = 0; c < 3; ++c) {
      float s = block_sum(a[c], red, tid);
      if (tid == 0) dst[c] = s / (float)cV;
      __syncthreads();
    }
  } else if (blk <= cP + 64) {
    const int idx = (blk - (cP + 1)) * 256 + tid;  // over cBN
    const float x = target[idx * 3 + 0];
    const float y = target[idx * 3 + 1];
    const float z = target[idx * 3 + 2];
    ((float4*)(ws + OFF_TGT4))[idx] =
        make_float4(x, y, z, 0.5f * fmaf(x, x, fmaf(y, y, z * z)));
  } else {
    const int bs = blk - (cP + 65);  // 0..127
    __shared__ float sM[cP][9];
    __shared__ float sC[3];
    __shared__ float sWT[cP][3];
    if (tid < cP) {
      const int p = tid;
      const float* t = transforms + (bs * cP + p) * 6;
      const float w = pw[bs * cP + p];
      const float sc = scales[bs];
      const float a = t[3], b = t[4], c = t[5];
      const float ca = cosf(a), sa = sinf(a);
      const float cb = cosf(b), sb = sinf(b);
      const float cg = cosf(c), sg = sinf(c);
      const float f = w * sc;
      sM[p][0] = f * (cb * cg);
      sM[p][1] = f * (-cb * sg);
      sM[p][2] = f * (sb);
      sM[p][3] = f * (ca * sg + sa * sb * cg);
      sM[p][4] = f * (ca * cg - sa * sb * sg);
      sM[p][5] = f * (-sa * cb);
      sM[p][6] = f * (sa * sg - ca * sb * cg);
      sM[p][7] = f * (sa * cg + ca * sb * sg);
      sM[p][8] = f * (ca * cb);
      sWT[p][0] = w * t[0];
      sWT[p][1] = w * t[1];
      sWT[p][2] = w * t[2];
    }
    __syncthreads();
    if (tid < 3) {
      float s = 0.f;
      for (int p = 0; p < cP; ++p) s += sWT[p][tid];
      sC[tid] = s;
    }
    __syncthreads();
    // persist sM / sC for k_final's centroid pass
    if (tid < cP * 9) ws[OFF_SM + bs * 288 + tid] = ((const float*)sM)[tid];
    if (tid < 3) ws[OFF_SC + bs * 3 + tid] = sC[tid];
    for (int k = tid; k < cK; k += 256) {
      const float x0 = verts[k * 3 + 0], x1 = verts[k * 3 + 1], x2 = verts[k * 3 + 2];
      float a0 = sC[0], a1 = sC[1], a2 = sC[2];
#pragma unroll 8
      for (int p = 0; p < cP; ++p) {
        const float* o = offs + (p * cV + k) * 3;
        const float d0 = x0 + o[0], d1 = x1 + o[1], d2 = x2 + o[2];
        a0 = fmaf(sM[p][0], d0, fmaf(sM[p][1], d1, fmaf(sM[p][2], d2, a0)));
        a1 = fmaf(sM[p][3], d0, fmaf(sM[p][4], d1, fmaf(sM[p][5], d2, a1)));
        a2 = fmaf(sM[p][6], d0, fmaf(sM[p][7], d1, fmaf(sM[p][8], d2, a2)));
      }
      ((float4*)(ws + OFF_PRED4))[bs * cK + k] =
          make_float4(a0, a1, a2, 0.5f * fmaf(a0, a0, fmaf(a1, a1, a2 * a2)));
    }
  }
}

// ---------- kernel G: per-target partial top-3 s-values over a 500-j chunk ----------
// s = hp - t.p ; d2 = 2*(s + ht)  (monotone in s)
__global__ void __launch_bounds__(256) k_global(float* __restrict__ ws) {
  __shared__ float4 sP[cJCH];  // 8 KB
  const int nb = blockIdx.x, jc = blockIdx.y, b = blockIdx.z;
  const int tid = threadIdx.x;
  const float4* pr = (const float4*)(ws + OFF_PRED4) + b * cJ + jc * cJCH;
  for (int i = tid; i < cJCH; i += 256) sP[i] = pr[i];
  __syncthreads();
  const int n = nb * 256 + tid;  // 0..1023; second target at n+1024
  const float4* tg = (const float4*)(ws + OFF_TGT4) + b * cN;
  const float4 tA = tg[n];
  const float4 tB = tg[n + 1024];
  float a0 = FINF, a1 = FINF, a2 = FINF;
  float b0 = FINF, b1 = FINF, b2 = FINF;
#pragma unroll 4
  for (int j = 0; j < cJCH; ++j) {
    const float4 p = sP[j];
    const float sA = fmaf(-tA.x, p.x, fmaf(-tA.y, p.y, fmaf(-tA.z, p.z, p.w)));
    const float sB = fmaf(-tB.x, p.x, fmaf(-tB.y, p.y, fmaf(-tB.z, p.z, p.w)));
    top3_insert(a0, a1, a2, sA);
    top3_insert(b0, b1, b2, sB);
  }
  float* plane = ws + OFF_T3 + (jc * 3) * cBN;
  const int idxA = b * cN + n;
  plane[0 * cBN + idxA] = a0;
  plane[1 * cBN + idxA] = a1;
  plane[2 * cBN + idxA] = a2;
  plane[0 * cBN + idxA + 1024] = b0;
  plane[1 * cBN + idxA + 1024] = b1;
  plane[2 * cBN + idxA + 1024] = b2;
}

// ---------- kernel P: per-pred partial min of s over a 256-target chunk ----------
// s = ht - p.t ; min d2 = 2*(min s + hp)
__global__ void __launch_bounds__(256) k_perslot(float* __restrict__ ws) {
  __shared__ float4 sT[cNCH];  // 4 KB
  const int jb = blockIdx.x;   // 8 j-blocks of 1024
  const int nc = blockIdx.y;   // 8 target chunks
  const int b = blockIdx.z;
  const int tid = threadIdx.x;
  const float4* tg = (const float4*)(ws + OFF_TGT4) + b * cN + nc * cNCH;
  sT[tid] = tg[tid];
  __syncthreads();
  const float4* pr = (const float4*)(ws + OFF_PRED4) + b * cJ;
  float px[4], py[4], pz[4];
  float m[4] = {FINF, FINF, FINF, FINF};
#pragma unroll
  for (int q = 0; q < 4; ++q) {
    int j = jb * 1024 + q * 256 + tid;
    j = (j < cJ) ? j : (cJ - 1);
    const float4 p = pr[j];
    px[q] = p.x; py[q] = p.y; pz[q] = p.z;
  }
#pragma unroll 2
  for (int n = 0; n < cNCH; ++n) {
    const float4 t = sT[n];
#pragma unroll
    for (int q = 0; q < 4; ++q) {
      const float s = fmaf(-px[q], t.x, fmaf(-py[q], t.y, fmaf(-pz[q], t.z, t.w)));
      m[q] = fminf(m[q], s);
    }
  }
  float* o = ws + OFF_PSP + (b * cNC + nc) * cJPAD + jb * 1024 + tid;
#pragma unroll
  for (int q = 0; q < 4; ++q) o[q * 256] = m[q];
}

// ---------- kernel MERGE: role-split ----------
// blk 0..63   : merge 16 partial top-3s per target (plane-major, coalesced), block-sum
// blk 64..319 : merge 8 chunk-mins per pred, add |p|^2, block-sum
__global__ void __launch_bounds__(256) k_merge(float* __restrict__ ws) {
  __shared__ float red[256];
  const int blk = blockIdx.x;
  const int tid = threadIdx.x;
  if (blk < 64) {
    const int idx = blk * 256 + tid;  // over cBN
    const float* plane = ws + OFF_T3;
    float t0 = FINF, t1 = FINF, t2 = FINF;
#pragma unroll
    for (int q = 0; q < cJC * 3; ++q)
      top3_insert(t0, t1, t2, plane[q * cBN + idx]);
    const float ht = ws[OFF_TGT4 + idx * 4 + 3];
    const float d0 = fmaxf(2.f * (t0 + ht), 0.f);
    const float d1 = fmaxf(2.f * (t1 + ht), 0.f);
    const float d2 = fmaxf(2.f * (t2 + ht), 0.f);
    const float s = block_sum(d0 + d1 + d2, red, tid);
    if (tid == 0) ws[OFF_GM + blk] = s;
  } else {
    const int rb = blk - 64;
    const int b = rb >> 5;             // /32
    const int jb = rb & 31;
    const int j = jb * 256 + tid;      // 0..8191
    float contrib = 0.f;
    if (j < cJ) {
      float m = FINF;
#pragma unroll
      for (int nc = 0; nc < cNC; ++nc)
        m = fminf(m, ws[OFF_PSP + (b * cNC + nc) * cJPAD + j]);
      const float hp = ws[OFF_PRED4 + (b * cJ + j) * 4 + 3];
      contrib = fmaxf(2.f * (m + hp), 0.f);
    }
    const float s = block_sum(contrib, red, tid);
    if (tid == 0) ws[OFF_PS + b * 32 + jb] = s;
  }
}

// ---------- kernel F: centroids + repulsion + combine ----------
__global__ void __launch_bounds__(256) k_final(float* __restrict__ ws, float* __restrict__ out) {
  __shared__ float red[256];
  __shared__ float scent[cB * cS * 3];
  const int tid = threadIdx.x;
  if (tid < cB * cS) {
    const int bs = tid;
    const float* M = ws + OFF_SM + bs * 288;
    const float* vb = ws + OFF_VBAR;
    float c0 = ws[OFF_SC + bs * 3 + 0];
    float c1 = ws[OFF_SC + bs * 3 + 1];
    float c2 = ws[OFF_SC + bs * 3 + 2];
#pragma unroll 8
    for (int p = 0; p < cP; ++p) {
      const float* ob = ws + OFF_OBAR + p * 3;
      const float d0 = vb[0] + ob[0], d1 = vb[1] + ob[1], d2 = vb[2] + ob[2];
      c0 = fmaf(M[p * 9 + 0], d0, fmaf(M[p * 9 + 1], d1, fmaf(M[p * 9 + 2], d2, c0)));
      c1 = fmaf(M[p * 9 + 3], d0, fmaf(M[p * 9 + 4], d1, fmaf(M[p * 9 + 5], d2, c1)));
      c2 = fmaf(M[p * 9 + 6], d0, fmaf(M[p * 9 + 7], d1, fmaf(M[p * 9 + 8], d2, c2)));
    }
    scent[bs * 3 + 0] = c0;
    scent[bs * 3 + 1] = c1;
    scent[bs * 3 + 2] = c2;
  }
  __syncthreads();
  float acc = 0.f;
  for (int idx = tid; idx < cB * cS * cS; idx += 256) {
    const int b = idx / (cS * cS);
    const int r = idx % (cS * cS);
    const int i = r / cS, jj = r % cS;
    if (i == jj) continue;
    const float* ci = scent + (b * cS + i) * 3;
    const float* cj = scent + (b * cS + jj) * 3;
    const float dx = ci[0] - cj[0], dy = ci[1] - cj[1], dz = ci[2] - cj[2];
    const float d = sqrtf(fmaf(dx, dx, fmaf(dy, dy, dz * dz)));
    acc += expf(5.0f * fmaxf(0.5f - d, 0.0f));
  }
  const float repsum = block_sum(acc, red, tid);
  __syncthreads();
  const float gsum = block_sum((tid < 64) ? ws[OFF_GM + tid] : 0.f, red, tid);
  __syncthreads();
  const float pssum = block_sum(ws[OFF_PS + tid], red, tid);
  if (tid == 0) {
    const float global_loss = gsum / (float)(cB * cN * 3);
    const float per_slot = pssum / (float)(cB * cS * cK);
    const float rep = repsum / (float)(cB * cS * (cS - 1));
    out[0] = 0.7f * global_loss + 0.3f * per_slot + 0.2f * rep;
  }
}

extern "C" void kernel_launch(void* const* d_in, const int* in_sizes, int n_in,
                              void* d_out, int out_size, void* d_ws, size_t ws_size,
                              hipStream_t stream) {
  const float* scales     = (const float*)d_in[0];
  const float* transforms = (const float*)d_in[1];
  const float* pw         = (const float*)d_in[2];
  const float* offs       = (const float*)d_in[3];
  const float* target     = (const float*)d_in[4];
  const float* verts      = (const float*)d_in[5];
  float* out = (float*)d_out;
  float* ws = (float*)d_ws;

  k_front<<<cP + 1 + 64 + cB * cS, 256, 0, stream>>>(scales, transforms, pw, offs,
                                                     verts, target, ws);
  k_global<<<dim3(cN / 512, cJC, cB), 256, 0, stream>>>(ws);
  k_perslot<<<dim3(cJPAD / 1024, cNC, cB), 256, 0, stream>>>(ws);
  k_merge<<<64 + 256, 256, 0, stream>>>(ws);
  k_final<<<1, 256, 0, stream>>>(ws, out);
}

// Round 4
// 66.457 us; speedup vs baseline: 3.3857x; 1.0278x over previous
//
#include <hip/hip_runtime.h>
#include <math.h>

namespace {
constexpr int cB = 8, cS = 16, cP = 32, cN = 2048, cV = 2562;
constexpr int cK = 500;              // K_SAMPLE
constexpr int cJ = cS * cK;          // 8000 pred points per batch
constexpr int cJC = 16;              // j-chunks for global role (500 each)
constexpr int cJCH = cJ / cJC;       // 500
constexpr int cNC = 16;              // target-chunks for perslot role (128 each)
constexpr int cNCH = cN / cNC;       // 128
constexpr int cJPAD = 8192;
constexpr int cBN = cB * cN;         // 16384
constexpr float FINF = 3.402823466e+38f;

// workspace layout (float offsets)
constexpr int OFF_PRED4 = 0;                         // cB*cJ*4 = 256000
constexpr int OFF_TGT4  = 256000;                    // cBN*4 = 65536
constexpr int OFF_VBAR  = 321536;                    // 4
constexpr int OFF_OBAR  = 321540;                    // 96
constexpr int OFF_SM    = 321664;                    // 128*288 = 36864
constexpr int OFF_SC    = 358528;                    // 384
constexpr int OFF_T3    = 358912;                    // 48*cBN = 786432 (plane-major)
constexpr int OFF_PSP   = 1145344;                   // cB*cNC*cJPAD = 1048576
constexpr int OFF_GM    = 2193920;                   // 64
constexpr int OFF_PS    = 2193984;                   // 256
} // namespace

__device__ __forceinline__ float block_sum(float v, float* red, int tid) {
  red[tid] = v;
  __syncthreads();
  for (int s = 128; s > 0; s >>= 1) {
    if (tid < s) red[tid] += red[tid + s];
    __syncthreads();
  }
  return red[0];
}

// branchless sorted top-3 insert, 3 VALU ops (min + 2x med3)
__device__ __forceinline__ void top3_insert(float& t0, float& t1, float& t2, float d) {
  const float n1 = __builtin_amdgcn_fmed3f(t0, t1, d);
  const float n2 = __builtin_amdgcn_fmed3f(t1, t2, d);
  t0 = fminf(t0, d);
  t1 = n1;
  t2 = n2;
}

// ---------- kernel FRONT: role-split ----------
// blk 0..32   : per-prototype mean offsets (+ mean vertex)
// blk 33..96  : target float4 (x,y,z, |t|^2/2)
// blk 97..224 : pred float4 for bs = blk-97, store sM / sC
__global__ void __launch_bounds__(256) k_front(const float* __restrict__ scales,
                                               const float* __restrict__ transforms,
                                               const float* __restrict__ pw,
                                               const float* __restrict__ offs,
                                               const float* __restrict__ verts,
                                               const float* __restrict__ target,
                                               float* __restrict__ ws) {
  const int blk = blockIdx.x;
  const int tid = threadIdx.x;
  if (blk <= cP) {
    __shared__ float red[256];
    const float* src = (blk < cP) ? (offs + blk * cV * 3) : verts;
    float acc0 = 0.f, acc1 = 0.f, acc2 = 0.f;
    for (int v = tid; v < cV; v += 256) {
      acc0 += src[v * 3 + 0];
      acc1 += src[v * 3 + 1];
      acc2 += src[v * 3 + 2];
    }
    float* dst = (blk < cP) ? (ws + OFF_OBAR + blk * 3) : (ws + OFF_VBAR);
    float a[3] = {acc0, acc1, acc2};
    for (int c = 0; c < 3; ++c) {
      float s = block_sum(a[c], red, tid);
      if (tid == 0) dst[c] = s / (float)cV;
      __syncthreads();
    }
  } else if (blk <= cP + 64) {
    const int idx = (blk - (cP + 1)) * 256 + tid;  // over cBN
    const float x = target[idx * 3 + 0];
    const float y = target[idx * 3 + 1];
    const float z = target[idx * 3 + 2];
    ((float4*)(ws + OFF_TGT4))[idx] =
        make_float4(x, y, z, 0.5f * fmaf(x, x, fmaf(y, y, z * z)));
  } else {
    const int bs = blk - (cP + 65);  // 0..127
    __shared__ float sM[cP][9];
    __shared__ float sC[3];
    __shared__ float sWT[cP][3];
    if (tid < cP) {
      const int p = tid;
      const float* t = transforms + (bs * cP + p) * 6;
      const float w = pw[bs * cP + p];
      const float sc = scales[bs];
      const float a = t[3], b = t[4], c = t[5];
      const float ca = cosf(a), sa = sinf(a);
      const float cb = cosf(b), sb = sinf(b);
      const float cg = cosf(c), sg = sinf(c);
      const float f = w * sc;
      sM[p][0] = f * (cb * cg);
      sM[p][1] = f * (-cb * sg);
      sM[p][2] = f * (sb);
      sM[p][3] = f * (ca * sg + sa * sb * cg);
      sM[p][4] = f * (ca * cg - sa * sb * sg);
      sM[p][5] = f * (-sa * cb);
      sM[p][6] = f * (sa * sg - ca * sb * cg);
      sM[p][7] = f * (sa * cg + ca * sb * sg);
      sM[p][8] = f * (ca * cb);
      sWT[p][0] = w * t[0];
      sWT[p][1] = w * t[1];
      sWT[p][2] = w * t[2];
    }
    __syncthreads();
    if (tid < 3) {
      float s = 0.f;
      for (int p = 0; p < cP; ++p) s += sWT[p][tid];
      sC[tid] = s;
    }
    __syncthreads();
    if (tid < cP * 9) ws[OFF_SM + bs * 288 + tid] = ((const float*)sM)[tid];
    if (tid < 3) ws[OFF_SC + bs * 3 + tid] = sC[tid];
    for (int k = tid; k < cK; k += 256) {
      const float x0 = verts[k * 3 + 0], x1 = verts[k * 3 + 1], x2 = verts[k * 3 + 2];
      float a0 = sC[0], a1 = sC[1], a2 = sC[2];
#pragma unroll 8
      for (int p = 0; p < cP; ++p) {
        const float* o = offs + (p * cV + k) * 3;
        const float d0 = x0 + o[0], d1 = x1 + o[1], d2 = x2 + o[2];
        a0 = fmaf(sM[p][0], d0, fmaf(sM[p][1], d1, fmaf(sM[p][2], d2, a0)));
        a1 = fmaf(sM[p][3], d0, fmaf(sM[p][4], d1, fmaf(sM[p][5], d2, a1)));
        a2 = fmaf(sM[p][6], d0, fmaf(sM[p][7], d1, fmaf(sM[p][8], d2, a2)));
      }
      ((float4*)(ws + OFF_PRED4))[bs * cK + k] =
          make_float4(a0, a1, a2, 0.5f * fmaf(a0, a0, fmaf(a1, a1, a2 * a2)));
    }
  }
}

// ---------- kernel DIST: fused role-split distance pass ----------
// blk 0..255  : global role. 500-j LDS tile, 4 targets/thread, top-3 of s.
// blk 256..767: perslot role. 128-target LDS tile, 8 preds/thread, min of s.
__global__ void __launch_bounds__(256) k_dist(float* __restrict__ ws) {
  __shared__ float4 sBuf[cJCH];  // 8 KB (perslot role uses first 128)
  const int blk = blockIdx.x;
  const int tid = threadIdx.x;
  if (blk < 256) {
    const int nb = blk & 1;
    const int jc = (blk >> 1) & 15;
    const int b = blk >> 5;
    const float4* pr = (const float4*)(ws + OFF_PRED4) + b * cJ + jc * cJCH;
    for (int i = tid; i < cJCH; i += 256) sBuf[i] = pr[i];
    __syncthreads();
    const int n0 = nb * 1024 + tid;
    const float4* tg = (const float4*)(ws + OFF_TGT4) + b * cN;
    const float4 tA = tg[n0];
    const float4 tB = tg[n0 + 256];
    const float4 tC = tg[n0 + 512];
    const float4 tD = tg[n0 + 768];
    float a0 = FINF, a1 = FINF, a2 = FINF;
    float b0 = FINF, b1 = FINF, b2 = FINF;
    float c0 = FINF, c1 = FINF, c2 = FINF;
    float d0 = FINF, d1 = FINF, d2 = FINF;
#pragma unroll 2
    for (int j = 0; j < cJCH; ++j) {
      const float4 p = sBuf[j];
      const float sA = fmaf(-tA.x, p.x, fmaf(-tA.y, p.y, fmaf(-tA.z, p.z, p.w)));
      const float sB = fmaf(-tB.x, p.x, fmaf(-tB.y, p.y, fmaf(-tB.z, p.z, p.w)));
      const float sC_ = fmaf(-tC.x, p.x, fmaf(-tC.y, p.y, fmaf(-tC.z, p.z, p.w)));
      const float sD = fmaf(-tD.x, p.x, fmaf(-tD.y, p.y, fmaf(-tD.z, p.z, p.w)));
      top3_insert(a0, a1, a2, sA);
      top3_insert(b0, b1, b2, sB);
      top3_insert(c0, c1, c2, sC_);
      top3_insert(d0, d1, d2, sD);
    }
    float* plane = ws + OFF_T3 + (jc * 3) * cBN;
    const int idx = b * cN + n0;
    plane[0 * cBN + idx] = a0;
    plane[1 * cBN + idx] = a1;
    plane[2 * cBN + idx] = a2;
    plane[0 * cBN + idx + 256] = b0;
    plane[1 * cBN + idx + 256] = b1;
    plane[2 * cBN + idx + 256] = b2;
    plane[0 * cBN + idx + 512] = c0;
    plane[1 * cBN + idx + 512] = c1;
    plane[2 * cBN + idx + 512] = c2;
    plane[0 * cBN + idx + 768] = d0;
    plane[1 * cBN + idx + 768] = d1;
    plane[2 * cBN + idx + 768] = d2;
  } else {
    const int rb = blk - 256;
    const int jb = rb & 3;
    const int nc = (rb >> 2) & 15;
    const int b = rb >> 6;
    const float4* tg = (const float4*)(ws + OFF_TGT4) + b * cN + nc * cNCH;
    if (tid < cNCH) sBuf[tid] = tg[tid];
    __syncthreads();
    const float4* pr = (const float4*)(ws + OFF_PRED4) + b * cJ;
    float px[8], py[8], pz[8];
    float m[8] = {FINF, FINF, FINF, FINF, FINF, FINF, FINF, FINF};
#pragma unroll
    for (int q = 0; q < 8; ++q) {
      int j = jb * 2048 + q * 256 + tid;
      j = (j < cJ) ? j : (cJ - 1);
      const float4 p = pr[j];
      px[q] = p.x; py[q] = p.y; pz[q] = p.z;
    }
#pragma unroll 2
    for (int n = 0; n < cNCH; ++n) {
      const float4 t = sBuf[n];
#pragma unroll
      for (int q = 0; q < 8; ++q) {
        const float s = fmaf(-px[q], t.x, fmaf(-py[q], t.y, fmaf(-pz[q], t.z, t.w)));
        m[q] = fminf(m[q], s);
      }
    }
    float* o = ws + OFF_PSP + (b * cNC + nc) * cJPAD + jb * 2048 + tid;
#pragma unroll
    for (int q = 0; q < 8; ++q) o[q * 256] = m[q];
  }
}

// ---------- kernel MERGE: role-split ----------
// blk 0..63   : merge 16 partial top-3s per target (plane-major), block-sum
// blk 64..319 : merge 16 chunk-mins per pred, add |p|^2, block-sum
__global__ void __launch_bounds__(256) k_merge(float* __restrict__ ws) {
  __shared__ float red[256];
  const int blk = blockIdx.x;
  const int tid = threadIdx.x;
  if (blk < 64) {
    const int idx = blk * 256 + tid;  // over cBN
    const float* plane = ws + OFF_T3;
    float t0 = FINF, t1 = FINF, t2 = FINF;
#pragma unroll
    for (int q = 0; q < cJC * 3; ++q)
      top3_insert(t0, t1, t2, plane[q * cBN + idx]);
    const float ht = ws[OFF_TGT4 + idx * 4 + 3];
    const float d0 = fmaxf(2.f * (t0 + ht), 0.f);
    const float d1 = fmaxf(2.f * (t1 + ht), 0.f);
    const float d2 = fmaxf(2.f * (t2 + ht), 0.f);
    const float s = block_sum(d0 + d1 + d2, red, tid);
    if (tid == 0) ws[OFF_GM + blk] = s;
  } else {
    const int rb = blk - 64;
    const int b = rb >> 5;
    const int jb = rb & 31;
    const int j = jb * 256 + tid;  // 0..8191
    float contrib = 0.f;
    if (j < cJ) {
      float m = FINF;
#pragma unroll
      for (int nc = 0; nc < cNC; ++nc)
        m = fminf(m, ws[OFF_PSP + (b * cNC + nc) * cJPAD + j]);
      const float hp = ws[OFF_PRED4 + (b * cJ + j) * 4 + 3];
      contrib = fmaxf(2.f * (m + hp), 0.f);
    }
    const float s = block_sum(contrib, red, tid);
    if (tid == 0) ws[OFF_PS + b * 32 + jb] = s;
  }
}

// ---------- kernel F: centroids + repulsion + combine ----------
__global__ void __launch_bounds__(256) k_final(float* __restrict__ ws, float* __restrict__ out) {
  __shared__ float red[256];
  __shared__ float scent[cB * cS * 3];
  const int tid = threadIdx.x;
  if (tid < cB * cS) {
    const int bs = tid;
    const float* M = ws + OFF_SM + bs * 288;
    const float* vb = ws + OFF_VBAR;
    float c0 = ws[OFF_SC + bs * 3 + 0];
    float c1 = ws[OFF_SC + bs * 3 + 1];
    float c2 = ws[OFF_SC + bs * 3 + 2];
#pragma unroll 8
    for (int p = 0; p < cP; ++p) {
      const float* ob = ws + OFF_OBAR + p * 3;
      const float d0 = vb[0] + ob[0], d1 = vb[1] + ob[1], d2 = vb[2] + ob[2];
      c0 = fmaf(M[p * 9 + 0], d0, fmaf(M[p * 9 + 1], d1, fmaf(M[p * 9 + 2], d2, c0)));
      c1 = fmaf(M[p * 9 + 3], d0, fmaf(M[p * 9 + 4], d1, fmaf(M[p * 9 + 5], d2, c1)));
      c2 = fmaf(M[p * 9 + 6], d0, fmaf(M[p * 9 + 7], d1, fmaf(M[p * 9 + 8], d2, c2)));
    }
    scent[bs * 3 + 0] = c0;
    scent[bs * 3 + 1] = c1;
    scent[bs * 3 + 2] = c2;
  }
  __syncthreads();
  float acc = 0.f;
  for (int idx = tid; idx < cB * cS * cS; idx += 256) {
    const int b = idx / (cS * cS);
    const int r = idx % (cS * cS);
    const int i = r / cS, jj = r % cS;
    if (i == jj) continue;
    const float* ci = scent + (b * cS + i) * 3;
    const float* cj = scent + (b * cS + jj) * 3;
    const float dx = ci[0] - cj[0], dy = ci[1] - cj[1], dz = ci[2] - cj[2];
    const float d = sqrtf(fmaf(dx, dx, fmaf(dy, dy, dz * dz)));
    acc += expf(5.0f * fmaxf(0.5f - d, 0.0f));
  }
  const float repsum = block_sum(acc, red, tid);
  __syncthreads();
  const float gsum = block_sum((tid < 64) ? ws[OFF_GM + tid] : 0.f, red, tid);
  __syncthreads();
  const float pssum = block_sum(ws[OFF_PS + tid], red, tid);
  if (tid == 0) {
    const float global_loss = gsum / (float)(cB * cN * 3);
    const float per_slot = pssum / (float)(cB * cS * cK);
    const float rep = repsum / (float)(cB * cS * (cS - 1));
    out[0] = 0.7f * global_loss + 0.3f * per_slot + 0.2f * rep;
  }
}

extern "C" void kernel_launch(void* const* d_in, const int* in_sizes, int n_in,
                              void* d_out, int out_size, void* d_ws, size_t ws_size,
                              hipStream_t stream) {
  const float* scales     = (const float*)d_in[0];
  const float* transforms = (const float*)d_in[1];
  const float* pw         = (const float*)d_in[2];
  const float* offs       = (const float*)d_in[3];
  const float* target     = (const float*)d_in[4];
  const float* verts      = (const float*)d_in[5];
  float* out = (float*)d_out;
  float* ws = (float*)d_ws;

  k_front<<<cP + 1 + 64 + cB * cS, 256, 0, stream>>>(scales, transforms, pw, offs,
                                                     verts, target, ws);
  k_dist<<<768, 256, 0, stream>>>(ws);
  k_merge<<<64 + 256, 256, 0, stream>>>(ws);
  k_final<<<1, 256, 0, stream>>>(ws, out);
}